// Round 4
// baseline (1789.747 us; speedup 1.0000x reference)
//
#include <hip/hip_runtime.h>
#include <math.h>

#define NN 100000
#define EE 1200000
#define DD 64
#define GG 128
#define LL 3
#define TOT (EE + NN)
#define NB_SCAN ((NN + 1023) / 1024)   // 98
#define BN_EPS 1e-5f
#define ENC_NEG_INF 0x007FFFFFu        // enc(-inf)

__device__ __forceinline__ unsigned enc_f(float x) {
    unsigned u = __float_as_uint(x);
    return (u & 0x80000000u) ? ~u : (u | 0x80000000u);
}
__device__ __forceinline__ float dec_f(unsigned e) {
    return (e & 0x80000000u) ? __uint_as_float(e ^ 0x80000000u)
                             : __uint_as_float(~e);
}

// ---- graph preprocessing -------------------------------------------------

__global__ void k_init(int* cnt, float* stats, unsigned* ge) {
    int i = blockIdx.x * blockDim.x + threadIdx.x;
    if (i < NN) cnt[i] = 1;                 // self-loop
    if (i < LL * 2 * DD) stats[i] = 0.f;
    if (i < GG * DD) ge[i] = ENC_NEG_INF;
}

__global__ void k_count(const int* __restrict__ dst, int* cnt) {
    int e = blockIdx.x * blockDim.x + threadIdx.x;
    if (e < EE) atomicAdd(&cnt[dst[e]], 1);
}

__global__ void k_scan_a(const int* __restrict__ cnt, int* ptr, int* bsum) {
    __shared__ int s[1024];
    int t = threadIdx.x;
    int i = blockIdx.x * 1024 + t;
    int v = (i < NN) ? cnt[i] : 0;
    s[t] = v;
    __syncthreads();
    for (int off = 1; off < 1024; off <<= 1) {
        int add = (t >= off) ? s[t - off] : 0;
        __syncthreads();
        s[t] += add;
        __syncthreads();
    }
    if (i < NN) ptr[i] = s[t] - v;          // block-local exclusive
    if (t == 1023) bsum[blockIdx.x] = s[1023];
}

__global__ void k_scan_b(int* bsum, int* ptr) {
    if (blockIdx.x == 0 && threadIdx.x == 0) {
        int run = 0;
        for (int b = 0; b < NB_SCAN; b++) { int t = bsum[b]; bsum[b] = run; run += t; }
        ptr[NN] = TOT;
    }
}

__global__ void k_scan_c(int* ptr, int* cursor, const int* __restrict__ cnt,
                         float* dinv, const int* __restrict__ bsum) {
    int i = blockIdx.x * 1024 + threadIdx.x;
    if (i < NN) {
        int p = ptr[i] + bsum[blockIdx.x];
        ptr[i] = p;
        cursor[i] = p;
        dinv[i] = rsqrtf((float)cnt[i]);
    }
}

__global__ void k_fill(const int* __restrict__ src, const int* __restrict__ dst,
                       int* cursor, int* col) {
    int i = blockIdx.x * blockDim.x + threadIdx.x;
    if (i >= TOT) return;
    int s, d;
    if (i < EE) { s = src[i]; d = dst[i]; }
    else        { s = d = i - EE; }          // self-loops
    int pos = atomicAdd(&cursor[d], 1);
    col[pos] = s;
}

// ---- dense matvec: out[n,:] = h[n,:] @ W  (wave per node, lane = out feat)

__global__ void k_mm(const float* __restrict__ h, const float* __restrict__ W,
                     float* __restrict__ out) {
    int lane = threadIdx.x & 63;
    int wid = (blockIdx.x * blockDim.x + threadIdx.x) >> 6;
    int nw = (gridDim.x * blockDim.x) >> 6;
    int per = (NN + nw - 1) / nw;
    int n0 = wid * per, n1 = min(n0 + per, NN);
    for (int n = n0; n < n1; n++) {
        float v = h[n * DD + lane];
        float acc = 0.f;
        #pragma unroll
        for (int k = 0; k < DD; k++)
            acc = fmaf(__shfl(v, k, 64), W[k * DD + lane], acc);
        out[n * DD + lane] = acc;
    }
}

// ---- SpMM: agg[n,:] = sum_e norm_e * hw[col_e,:] + bias, + BN stats ------

__global__ void k_spmm(const float* __restrict__ hw, const int* __restrict__ ptr,
                       const int* __restrict__ col, const float* __restrict__ dinv,
                       const float* __restrict__ bias, float* __restrict__ agg,
                       float* __restrict__ stats) {
    int lane = threadIdx.x & 63;
    int wid = (blockIdx.x * blockDim.x + threadIdx.x) >> 6;
    int nw = (gridDim.x * blockDim.x) >> 6;
    int per = (NN + nw - 1) / nw;
    int n0 = wid * per, n1 = min(n0 + per, NN);
    float b = bias[lane];
    float s1 = 0.f, s2 = 0.f;
    for (int n = n0; n < n1; n++) {
        int p0 = ptr[n], p1 = ptr[n + 1];
        float dn = dinv[n];
        float acc0 = 0.f, acc1 = 0.f;
        for (int base = p0; base < p1; base += 64) {
            int cnt = min(64, p1 - base);
            int c_l = 0; float w_l = 0.f;
            if (lane < cnt) { c_l = col[base + lane]; w_l = dinv[c_l]; }
            int j = 0;
            for (; j + 1 < cnt; j += 2) {
                int   c0 = __shfl(c_l, j, 64),     c1 = __shfl(c_l, j + 1, 64);
                float w0 = __shfl(w_l, j, 64),     w1 = __shfl(w_l, j + 1, 64);
                acc0 = fmaf(w0 * dn, hw[c0 * DD + lane], acc0);
                acc1 = fmaf(w1 * dn, hw[c1 * DD + lane], acc1);
            }
            if (j < cnt) {
                int   c0 = __shfl(c_l, j, 64);
                float w0 = __shfl(w_l, j, 64);
                acc0 = fmaf(w0 * dn, hw[c0 * DD + lane], acc0);
            }
        }
        float o = acc0 + acc1 + b;
        agg[n * DD + lane] = o;
        s1 += o;
        s2 = fmaf(o, o, s2);
    }
    __shared__ float red[512];
    int t = threadIdx.x;                     // blockDim == 256
    red[t] = s1;
    red[256 + t] = s2;
    __syncthreads();
    if (t < 64) {
        float a1 = red[t] + red[64 + t] + red[128 + t] + red[192 + t];
        float a2 = red[256 + t] + red[320 + t] + red[384 + t] + red[448 + t];
        atomicAdd(&stats[t], a1);
        atomicAdd(&stats[DD + t], a2);
    }
}

// ---- fused BN+ReLU then matvec with next layer's W -----------------------

__global__ void k_bnmm(const float* __restrict__ agg, const float* __restrict__ stats,
                       const float* __restrict__ g, const float* __restrict__ bb,
                       const float* __restrict__ W, float* __restrict__ out) {
    int lane = threadIdx.x & 63;
    int wid = (blockIdx.x * blockDim.x + threadIdx.x) >> 6;
    int nw = (gridDim.x * blockDim.x) >> 6;
    int per = (NN + nw - 1) / nw;
    int n0 = wid * per, n1 = min(n0 + per, NN);
    const float invN = 1.f / (float)NN;
    float mu = stats[lane] * invN;
    float var = stats[DD + lane] * invN - mu * mu;
    float sc = g[lane] * rsqrtf(var + BN_EPS);
    float sh = bb[lane] - mu * sc;
    for (int n = n0; n < n1; n++) {
        float y = fmaf(agg[n * DD + lane], sc, sh);
        y = fmaxf(y, 0.f);
        float acc = 0.f;
        #pragma unroll
        for (int k = 0; k < DD; k++)
            acc = fmaf(__shfl(y, k, 64), W[k * DD + lane], acc);
        out[n * DD + lane] = acc;
    }
}

// ---- last layer: BN+ReLU (node emb in-place) + fc1 + fc2 + seg-max -------
// batch is SORTED: keep a per-lane running max per graph-run, flush once per
// run with atomicMax. Cuts atomics ~12x vs per-node flushing.

__global__ void k_bnfc(float* __restrict__ h, const float* __restrict__ stats,
                       const float* __restrict__ g, const float* __restrict__ bb,
                       const float* __restrict__ fc1w, const float* __restrict__ fc1b,
                       const float* __restrict__ fc2w, const float* __restrict__ fc2b,
                       const int* __restrict__ batch, unsigned* ge) {
    int lane = threadIdx.x & 63;
    int wid = (blockIdx.x * blockDim.x + threadIdx.x) >> 6;
    int nw = (gridDim.x * blockDim.x) >> 6;
    int per = (NN + nw - 1) / nw;
    int n0 = wid * per, n1 = min(n0 + per, NN);
    if (n0 >= NN) return;
    const float invN = 1.f / (float)NN;
    float mu = stats[lane] * invN;
    float var = stats[DD + lane] * invN - mu * mu;
    float sc = g[lane] * rsqrtf(var + BN_EPS);
    float sh = bb[lane] - mu * sc;
    float b1 = fc1b[lane], b2 = fc2b[lane];
    int curg = batch[n0];
    float runmax = -INFINITY;
    for (int n = n0; n < n1; n++) {
        float y = fmaf(h[n * DD + lane], sc, sh);
        y = fmaxf(y, 0.f);
        h[n * DD + lane] = y;                // node_embeddings (in-place over agg)
        float o1 = b1;
        #pragma unroll
        for (int k = 0; k < DD; k++)
            o1 = fmaf(__shfl(y, k, 64), fc1w[k * DD + lane], o1);
        float o2 = b2;
        #pragma unroll
        for (int k = 0; k < DD; k++)
            o2 = fmaf(__shfl(o1, k, 64), fc2w[k * DD + lane], o2);
        int bg = batch[n];                   // wave-uniform branch (sorted batch)
        if (bg != curg) {
            atomicMax(&ge[curg * DD + lane], enc_f(runmax));
            curg = bg;
            runmax = o2;
        } else {
            runmax = fmaxf(runmax, o2);
        }
    }
    atomicMax(&ge[curg * DD + lane], enc_f(runmax));
}

// ---- readout: decode seg-max, fc3, log_softmax ---------------------------

__global__ void k_final(const unsigned* __restrict__ ge, const float* __restrict__ fc3w,
                        const float* __restrict__ fc3b, float* __restrict__ out_ge,
                        float* __restrict__ out_lg) {
    int g = blockIdx.x;          // 128 blocks
    int lane = threadIdx.x;      // 64 threads
    float f = dec_f(ge[g * DD + lane]);
    out_ge[g * DD + lane] = f;
    float v0 = f * fc3w[lane * 2 + 0];
    float v1 = f * fc3w[lane * 2 + 1];
    for (int off = 32; off; off >>= 1) {
        v0 += __shfl_xor(v0, off, 64);
        v1 += __shfl_xor(v1, off, 64);
    }
    if (lane == 0) {
        float l0 = v0 + fc3b[0], l1 = v1 + fc3b[1];
        float m = fmaxf(l0, l1);
        float lse = m + logf(expf(l0 - m) + expf(l1 - m));
        out_lg[g * 2 + 0] = l0 - lse;
        out_lg[g * 2 + 1] = l1 - lse;
    }
}

static inline size_t alup(size_t x) { return (x + 255) & ~(size_t)255; }

extern "C" void kernel_launch(void* const* d_in, const int* in_sizes, int n_in,
                              void* d_out, int out_size, void* d_ws, size_t ws_size,
                              hipStream_t stream) {
    const float* x      = (const float*)d_in[0];
    const int*   ei     = (const int*)d_in[1];
    const int*   srcI   = ei;
    const int*   dstI   = ei + EE;
    const int*   batch  = (const int*)d_in[2];
    const float* conv_w = (const float*)d_in[3];   // [3,64,64]
    const float* conv_b = (const float*)d_in[4];   // [3,64]
    const float* bn_g   = (const float*)d_in[5];
    const float* bn_b   = (const float*)d_in[6];
    const float* fc1w   = (const float*)d_in[7];
    const float* fc1b   = (const float*)d_in[8];
    const float* fc2w   = (const float*)d_in[9];
    const float* fc2b   = (const float*)d_in[10];
    const float* fc3w   = (const float*)d_in[11];
    const float* fc3b   = (const float*)d_in[12];

    char* w = (char*)d_ws;
    int*      cnt    = (int*)w;       w += alup(sizeof(int) * NN);
    int*      ptr    = (int*)w;       w += alup(sizeof(int) * (NN + 1));
    int*      cursor = (int*)w;       w += alup(sizeof(int) * NN);
    int*      bsum   = (int*)w;       w += alup(sizeof(int) * NB_SCAN);
    float*    dinv   = (float*)w;     w += alup(sizeof(float) * NN);
    int*      col    = (int*)w;       w += alup(sizeof(int) * TOT);
    float*    bufA   = (float*)w;     w += alup(sizeof(float) * NN * DD);
    float*    stats  = (float*)w;     w += alup(sizeof(float) * LL * 2 * DD);
    unsigned* ge     = (unsigned*)w;  w += alup(sizeof(unsigned) * GG * DD);

    float* out     = (float*)d_out;
    float* agg     = out;              // reuse node-embedding region as scratch
    float* out_ge  = out + (size_t)NN * DD;
    float* out_lg  = out_ge + GG * DD;

    const int BLK = 256;
    const int GRID_NODE = 2048;        // 8192 waves, contiguous chunks over nodes

    hipLaunchKernelGGL(k_init,   dim3((NN + BLK - 1) / BLK), dim3(BLK), 0, stream,
                       cnt, stats, ge);
    hipLaunchKernelGGL(k_count,  dim3((EE + BLK - 1) / BLK), dim3(BLK), 0, stream,
                       dstI, cnt);
    hipLaunchKernelGGL(k_scan_a, dim3(NB_SCAN), dim3(1024), 0, stream, cnt, ptr, bsum);
    hipLaunchKernelGGL(k_scan_b, dim3(1), dim3(64), 0, stream, bsum, ptr);
    hipLaunchKernelGGL(k_scan_c, dim3(NB_SCAN), dim3(1024), 0, stream,
                       ptr, cursor, cnt, dinv, bsum);
    hipLaunchKernelGGL(k_fill,   dim3((TOT + BLK - 1) / BLK), dim3(BLK), 0, stream,
                       srcI, dstI, cursor, col);

    // layer 0: hw = x @ W0
    hipLaunchKernelGGL(k_mm, dim3(GRID_NODE), dim3(BLK), 0, stream,
                       x, conv_w + 0 * DD * DD, bufA);
    hipLaunchKernelGGL(k_spmm, dim3(GRID_NODE), dim3(BLK), 0, stream,
                       bufA, ptr, col, dinv, conv_b + 0 * DD, agg, stats + 0 * 2 * DD);
    // BN0+ReLU fused with hw1 = h @ W1
    hipLaunchKernelGGL(k_bnmm, dim3(GRID_NODE), dim3(BLK), 0, stream,
                       agg, stats + 0 * 2 * DD, bn_g + 0 * DD, bn_b + 0 * DD,
                       conv_w + 1 * DD * DD, bufA);
    hipLaunchKernelGGL(k_spmm, dim3(GRID_NODE), dim3(BLK), 0, stream,
                       bufA, ptr, col, dinv, conv_b + 1 * DD, agg, stats + 1 * 2 * DD);
    hipLaunchKernelGGL(k_bnmm, dim3(GRID_NODE), dim3(BLK), 0, stream,
                       agg, stats + 1 * 2 * DD, bn_g + 1 * DD, bn_b + 1 * DD,
                       conv_w + 2 * DD * DD, bufA);
    hipLaunchKernelGGL(k_spmm, dim3(GRID_NODE), dim3(BLK), 0, stream,
                       bufA, ptr, col, dinv, conv_b + 2 * DD, agg, stats + 2 * 2 * DD);
    // BN2+ReLU (node emb in place) + fc1 + fc2 + segment-max
    hipLaunchKernelGGL(k_bnfc, dim3(GRID_NODE), dim3(BLK), 0, stream,
                       agg, stats + 2 * 2 * DD, bn_g + 2 * DD, bn_b + 2 * DD,
                       fc1w, fc1b, fc2w, fc2b, batch, ge);
    hipLaunchKernelGGL(k_final, dim3(GG), dim3(64), 0, stream,
                       ge, fc3w, fc3b, out_ge, out_lg);
}

// Round 5
// 1032.184 us; speedup vs baseline: 1.7339x; 1.7339x over previous
//
#include <hip/hip_runtime.h>
#include <math.h>

#define NN 100000
#define EE 1200000
#define DD 64
#define GG 128
#define LL 3
#define TOT (EE + NN)
#define NB_SCAN ((NN + 1023) / 1024)   // 98
#define BN_EPS 1e-5f
#define ENC_NEG_INF 0x007FFFFFu        // enc(-inf)
#define NPB_FC 128                      // nodes per block, k_bnfc
#define NPB_MM 256                      // nodes per block, k_lmm
#define GSLOTS 16                       // per-block graph slots for seg-max

__device__ __forceinline__ unsigned enc_f(float x) {
    unsigned u = __float_as_uint(x);
    return (u & 0x80000000u) ? ~u : (u | 0x80000000u);
}
__device__ __forceinline__ float dec_f(unsigned e) {
    return (e & 0x80000000u) ? __uint_as_float(e ^ 0x80000000u)
                             : __uint_as_float(~e);
}

// ---- graph preprocessing -------------------------------------------------

__global__ void k_init(int* cnt, float* stats, unsigned* ge) {
    int i = blockIdx.x * blockDim.x + threadIdx.x;
    if (i < NN) cnt[i] = 1;                 // self-loop
    if (i < LL * 2 * DD) stats[i] = 0.f;
    if (i < GG * DD) ge[i] = ENC_NEG_INF;
}

__global__ void k_count(const int* __restrict__ dst, int* cnt) {
    int e = blockIdx.x * blockDim.x + threadIdx.x;
    if (e < EE) atomicAdd(&cnt[dst[e]], 1);
}

__global__ void k_scan_a(const int* __restrict__ cnt, int* ptr, int* bsum) {
    __shared__ int s[1024];
    int t = threadIdx.x;
    int i = blockIdx.x * 1024 + t;
    int v = (i < NN) ? cnt[i] : 0;
    s[t] = v;
    __syncthreads();
    for (int off = 1; off < 1024; off <<= 1) {
        int add = (t >= off) ? s[t - off] : 0;
        __syncthreads();
        s[t] += add;
        __syncthreads();
    }
    if (i < NN) ptr[i] = s[t] - v;          // block-local exclusive
    if (t == 1023) bsum[blockIdx.x] = s[1023];
}

__global__ void k_scan_b(int* bsum, int* ptr) {
    if (blockIdx.x == 0 && threadIdx.x == 0) {
        int run = 0;
        for (int b = 0; b < NB_SCAN; b++) { int t = bsum[b]; bsum[b] = run; run += t; }
        ptr[NN] = TOT;
    }
}

__global__ void k_scan_c(int* ptr, int* cursor, const int* __restrict__ cnt,
                         float* dinv, const int* __restrict__ bsum) {
    int i = blockIdx.x * 1024 + threadIdx.x;
    if (i < NN) {
        int p = ptr[i] + bsum[blockIdx.x];
        ptr[i] = p;
        cursor[i] = p;
        dinv[i] = rsqrtf((float)cnt[i]);
    }
}

__global__ void k_fill(const int* __restrict__ src, const int* __restrict__ dst,
                       int* cursor, int* col) {
    int i = blockIdx.x * blockDim.x + threadIdx.x;
    if (i >= TOT) return;
    int s, d;
    if (i < EE) { s = src[i]; d = dst[i]; }
    else        { s = d = i - EE; }          // self-loops
    int pos = atomicAdd(&cursor[d], 1);
    col[pos] = s;
}

// ---- linear (+optional BN+ReLU): out[n,:] = act(h[n,:]) @ W --------------
// W staged in LDS once per block; 2-node ILP; wave=64 lanes, lane=out feat.

__global__ __launch_bounds__(256)
void k_lmm(const float* __restrict__ h, const float* __restrict__ stats,
           const float* __restrict__ g, const float* __restrict__ bb,
           const float* __restrict__ W, float* __restrict__ out, int apply_bn) {
    __shared__ float wl[DD * DD];           // 16 KB
    int t = threadIdx.x;
    for (int i = t; i < DD * DD / 4; i += 256)
        ((float4*)wl)[i] = ((const float4*)W)[i];
    __syncthreads();

    int lane = t & 63, wv = t >> 6;         // 4 waves/block
    int n0 = blockIdx.x * NPB_MM;
    int nend = min(n0 + NPB_MM, NN);
    float sc = 1.f, sh = 0.f;
    if (apply_bn) {
        const float invN = 1.f / (float)NN;
        float mu = stats[lane] * invN;
        float var = stats[DD + lane] * invN - mu * mu;
        sc = g[lane] * rsqrtf(var + BN_EPS);
        sh = bb[lane] - mu * sc;
    }
    for (int p = wv; ; p += 4) {
        int n = n0 + 2 * p;
        if (n >= nend) break;
        bool has2 = (n + 1 < nend);
        float y0 = h[n * DD + lane];
        float y1 = has2 ? h[(n + 1) * DD + lane] : 0.f;
        if (apply_bn) {
            y0 = fmaxf(fmaf(y0, sc, sh), 0.f);
            y1 = fmaxf(fmaf(y1, sc, sh), 0.f);
        }
        float a0 = 0.f, a1 = 0.f;
        #pragma unroll
        for (int k = 0; k < DD; k++) {
            float w = wl[k * DD + lane];
            a0 = fmaf(__shfl(y0, k, 64), w, a0);
            a1 = fmaf(__shfl(y1, k, 64), w, a1);
        }
        out[n * DD + lane] = a0;
        if (has2) out[(n + 1) * DD + lane] = a1;
    }
}

// ---- SpMM: agg[n,:] = sum_e norm_e * hw[col_e,:] + bias, + BN stats ------

__global__ void k_spmm(const float* __restrict__ hw, const int* __restrict__ ptr,
                       const int* __restrict__ col, const float* __restrict__ dinv,
                       const float* __restrict__ bias, float* __restrict__ agg,
                       float* __restrict__ stats) {
    int lane = threadIdx.x & 63;
    int wid = (blockIdx.x * blockDim.x + threadIdx.x) >> 6;
    int nw = (gridDim.x * blockDim.x) >> 6;
    int per = (NN + nw - 1) / nw;
    int n0 = wid * per, n1 = min(n0 + per, NN);
    float b = bias[lane];
    float s1 = 0.f, s2 = 0.f;
    for (int n = n0; n < n1; n++) {
        int p0 = ptr[n], p1 = ptr[n + 1];
        float dn = dinv[n];
        float acc0 = 0.f, acc1 = 0.f;
        for (int base = p0; base < p1; base += 64) {
            int cnt = min(64, p1 - base);
            int c_l = 0; float w_l = 0.f;
            if (lane < cnt) { c_l = col[base + lane]; w_l = dinv[c_l]; }
            int j = 0;
            for (; j + 1 < cnt; j += 2) {
                int   c0 = __shfl(c_l, j, 64),     c1 = __shfl(c_l, j + 1, 64);
                float w0 = __shfl(w_l, j, 64),     w1 = __shfl(w_l, j + 1, 64);
                acc0 = fmaf(w0 * dn, hw[c0 * DD + lane], acc0);
                acc1 = fmaf(w1 * dn, hw[c1 * DD + lane], acc1);
            }
            if (j < cnt) {
                int   c0 = __shfl(c_l, j, 64);
                float w0 = __shfl(w_l, j, 64);
                acc0 = fmaf(w0 * dn, hw[c0 * DD + lane], acc0);
            }
        }
        float o = acc0 + acc1 + b;
        agg[n * DD + lane] = o;
        s1 += o;
        s2 = fmaf(o, o, s2);
    }
    __shared__ float red[512];
    int t = threadIdx.x;                     // blockDim == 256
    red[t] = s1;
    red[256 + t] = s2;
    __syncthreads();
    if (t < 64) {
        float a1 = red[t] + red[64 + t] + red[128 + t] + red[192 + t];
        float a2 = red[256 + t] + red[320 + t] + red[384 + t] + red[448 + t];
        atomicAdd(&stats[t], a1);
        atomicAdd(&stats[DD + t], a2);
    }
}

// ---- last layer: BN+ReLU (node emb in-place) + fc1 + fc2 + seg-max -------
// fc1w/fc2w staged in LDS; seg-max accumulated in per-block LDS graph slots
// (block = 128 contiguous nodes spans ~1-2 graphs), drained once at the end.

__global__ __launch_bounds__(256)
void k_bnfc(float* __restrict__ h, const float* __restrict__ stats,
            const float* __restrict__ g, const float* __restrict__ bb,
            const float* __restrict__ fc1w, const float* __restrict__ fc1b,
            const float* __restrict__ fc2w, const float* __restrict__ fc2b,
            const int* __restrict__ batch, unsigned* ge) {
    __shared__ float w1[DD * DD];           // 16 KB
    __shared__ float w2[DD * DD];           // 16 KB
    __shared__ unsigned gmax[GSLOTS * DD];  // 4 KB
    int t = threadIdx.x;
    for (int i = t; i < DD * DD / 4; i += 256) {
        ((float4*)w1)[i] = ((const float4*)fc1w)[i];
        ((float4*)w2)[i] = ((const float4*)fc2w)[i];
    }
    for (int i = t; i < GSLOTS * DD; i += 256) gmax[i] = ENC_NEG_INF;
    __syncthreads();

    int lane = t & 63, wv = t >> 6;         // 4 waves/block
    int n0 = blockIdx.x * NPB_FC;
    int nend = min(n0 + NPB_FC, NN);
    int gbase = batch[n0];

    const float invN = 1.f / (float)NN;
    float mu = stats[lane] * invN;
    float var = stats[DD + lane] * invN - mu * mu;
    float sc = g[lane] * rsqrtf(var + BN_EPS);
    float sh = bb[lane] - mu * sc;
    float b1 = fc1b[lane], b2 = fc2b[lane];

    int curg = -1;
    float runmax = -INFINITY;
    for (int p = wv; ; p += 4) {
        int n = n0 + 2 * p;
        if (n >= nend) break;
        bool has2 = (n + 1 < nend);
        float y0 = fmaxf(fmaf(h[n * DD + lane], sc, sh), 0.f);
        float y1 = 0.f;
        h[n * DD + lane] = y0;               // node_embeddings in-place
        if (has2) {
            y1 = fmaxf(fmaf(h[(n + 1) * DD + lane], sc, sh), 0.f);
            h[(n + 1) * DD + lane] = y1;
        }
        float o1a = b1, o1b = b1;
        #pragma unroll
        for (int k = 0; k < DD; k++) {
            float w = w1[k * DD + lane];
            o1a = fmaf(__shfl(y0, k, 64), w, o1a);
            o1b = fmaf(__shfl(y1, k, 64), w, o1b);
        }
        float o2a = b2, o2b = b2;
        #pragma unroll
        for (int k = 0; k < DD; k++) {
            float w = w2[k * DD + lane];
            o2a = fmaf(__shfl(o1a, k, 64), w, o2a);
            o2b = fmaf(__shfl(o1b, k, 64), w, o2b);
        }
        int g0 = batch[n];                   // wave-uniform (n uniform)
        if (g0 != curg) {
            if (curg >= 0) {
                int s = curg - gbase;
                if (s < GSLOTS) atomicMax(&gmax[s * DD + lane], enc_f(runmax));
                else            atomicMax(&ge[curg * DD + lane], enc_f(runmax));
            }
            curg = g0; runmax = -INFINITY;
        }
        runmax = fmaxf(runmax, o2a);
        if (has2) {
            int g1 = batch[n + 1];
            if (g1 != curg) {
                int s = curg - gbase;
                if (s < GSLOTS) atomicMax(&gmax[s * DD + lane], enc_f(runmax));
                else            atomicMax(&ge[curg * DD + lane], enc_f(runmax));
                curg = g1; runmax = -INFINITY;
            }
            runmax = fmaxf(runmax, o2b);
        }
    }
    if (curg >= 0) {
        int s = curg - gbase;
        if (s < GSLOTS) atomicMax(&gmax[s * DD + lane], enc_f(runmax));
        else            atomicMax(&ge[curg * DD + lane], enc_f(runmax));
    }
    __syncthreads();
    for (int s = wv; s < GSLOTS; s += 4) {   // drain touched slots
        unsigned v = gmax[s * DD + lane];
        if (__any(v != ENC_NEG_INF))
            atomicMax(&ge[(gbase + s) * DD + lane], v);
    }
}

// ---- readout: decode seg-max, fc3, log_softmax ---------------------------

__global__ void k_final(const unsigned* __restrict__ ge, const float* __restrict__ fc3w,
                        const float* __restrict__ fc3b, float* __restrict__ out_ge,
                        float* __restrict__ out_lg) {
    int g = blockIdx.x;          // 128 blocks
    int lane = threadIdx.x;      // 64 threads
    float f = dec_f(ge[g * DD + lane]);
    out_ge[g * DD + lane] = f;
    float v0 = f * fc3w[lane * 2 + 0];
    float v1 = f * fc3w[lane * 2 + 1];
    for (int off = 32; off; off >>= 1) {
        v0 += __shfl_xor(v0, off, 64);
        v1 += __shfl_xor(v1, off, 64);
    }
    if (lane == 0) {
        float l0 = v0 + fc3b[0], l1 = v1 + fc3b[1];
        float m = fmaxf(l0, l1);
        float lse = m + logf(expf(l0 - m) + expf(l1 - m));
        out_lg[g * 2 + 0] = l0 - lse;
        out_lg[g * 2 + 1] = l1 - lse;
    }
}

static inline size_t alup(size_t x) { return (x + 255) & ~(size_t)255; }

extern "C" void kernel_launch(void* const* d_in, const int* in_sizes, int n_in,
                              void* d_out, int out_size, void* d_ws, size_t ws_size,
                              hipStream_t stream) {
    const float* x      = (const float*)d_in[0];
    const int*   ei     = (const int*)d_in[1];
    const int*   srcI   = ei;
    const int*   dstI   = ei + EE;
    const int*   batch  = (const int*)d_in[2];
    const float* conv_w = (const float*)d_in[3];   // [3,64,64]
    const float* conv_b = (const float*)d_in[4];   // [3,64]
    const float* bn_g   = (const float*)d_in[5];
    const float* bn_b   = (const float*)d_in[6];
    const float* fc1w   = (const float*)d_in[7];
    const float* fc1b   = (const float*)d_in[8];
    const float* fc2w   = (const float*)d_in[9];
    const float* fc2b   = (const float*)d_in[10];
    const float* fc3w   = (const float*)d_in[11];
    const float* fc3b   = (const float*)d_in[12];

    char* w = (char*)d_ws;
    int*      cnt    = (int*)w;       w += alup(sizeof(int) * NN);
    int*      ptr    = (int*)w;       w += alup(sizeof(int) * (NN + 1));
    int*      cursor = (int*)w;       w += alup(sizeof(int) * NN);
    int*      bsum   = (int*)w;       w += alup(sizeof(int) * NB_SCAN);
    float*    dinv   = (float*)w;     w += alup(sizeof(float) * NN);
    int*      col    = (int*)w;       w += alup(sizeof(int) * TOT);
    float*    bufA   = (float*)w;     w += alup(sizeof(float) * NN * DD);
    float*    stats  = (float*)w;     w += alup(sizeof(float) * LL * 2 * DD);
    unsigned* ge     = (unsigned*)w;  w += alup(sizeof(unsigned) * GG * DD);

    float* out     = (float*)d_out;
    float* agg     = out;              // reuse node-embedding region as scratch
    float* out_ge  = out + (size_t)NN * DD;
    float* out_lg  = out_ge + GG * DD;

    const int BLK = 256;
    const int GRID_SPMM = 2048;
    const int GRID_MM = (NN + NPB_MM - 1) / NPB_MM;   // 391
    const int GRID_FC = (NN + NPB_FC - 1) / NPB_FC;   // 782

    hipLaunchKernelGGL(k_init,   dim3((NN + BLK - 1) / BLK), dim3(BLK), 0, stream,
                       cnt, stats, ge);
    hipLaunchKernelGGL(k_count,  dim3((EE + BLK - 1) / BLK), dim3(BLK), 0, stream,
                       dstI, cnt);
    hipLaunchKernelGGL(k_scan_a, dim3(NB_SCAN), dim3(1024), 0, stream, cnt, ptr, bsum);
    hipLaunchKernelGGL(k_scan_b, dim3(1), dim3(64), 0, stream, bsum, ptr);
    hipLaunchKernelGGL(k_scan_c, dim3(NB_SCAN), dim3(1024), 0, stream,
                       ptr, cursor, cnt, dinv, bsum);
    hipLaunchKernelGGL(k_fill,   dim3((TOT + BLK - 1) / BLK), dim3(BLK), 0, stream,
                       srcI, dstI, cursor, col);

    // layer 0: hw = x @ W0
    hipLaunchKernelGGL(k_lmm, dim3(GRID_MM), dim3(BLK), 0, stream,
                       x, (const float*)nullptr, (const float*)nullptr,
                       (const float*)nullptr, conv_w + 0 * DD * DD, bufA, 0);
    hipLaunchKernelGGL(k_spmm, dim3(GRID_SPMM), dim3(BLK), 0, stream,
                       bufA, ptr, col, dinv, conv_b + 0 * DD, agg, stats + 0 * 2 * DD);
    // BN0+ReLU fused with hw1 = h @ W1
    hipLaunchKernelGGL(k_lmm, dim3(GRID_MM), dim3(BLK), 0, stream,
                       agg, stats + 0 * 2 * DD, bn_g + 0 * DD, bn_b + 0 * DD,
                       conv_w + 1 * DD * DD, bufA, 1);
    hipLaunchKernelGGL(k_spmm, dim3(GRID_SPMM), dim3(BLK), 0, stream,
                       bufA, ptr, col, dinv, conv_b + 1 * DD, agg, stats + 1 * 2 * DD);
    hipLaunchKernelGGL(k_lmm, dim3(GRID_MM), dim3(BLK), 0, stream,
                       agg, stats + 1 * 2 * DD, bn_g + 1 * DD, bn_b + 1 * DD,
                       conv_w + 2 * DD * DD, bufA, 1);
    hipLaunchKernelGGL(k_spmm, dim3(GRID_SPMM), dim3(BLK), 0, stream,
                       bufA, ptr, col, dinv, conv_b + 2 * DD, agg, stats + 2 * 2 * DD);
    // BN2+ReLU (node emb in place) + fc1 + fc2 + segment-max
    hipLaunchKernelGGL(k_bnfc, dim3(GRID_FC), dim3(BLK), 0, stream,
                       agg, stats + 2 * 2 * DD, bn_g + 2 * DD, bn_b + 2 * DD,
                       fc1w, fc1b, fc2w, fc2b, batch, ge);
    hipLaunchKernelGGL(k_final, dim3(GG), dim3(64), 0, stream,
                       ge, fc3w, fc3b, out_ge, out_lg);
}